// Round 1
// baseline (397.396 us; speedup 1.0000x reference)
//
#include <hip/hip_runtime.h>

// ---------------------------------------------------------------------------
// NeRF-style aggregator, MI355X (gfx950).
// Strategy: bf16 MFMA (fp32 accum) for all GEMM layers; fused per-block MLP
// with LDS ping-pong buffers; XOR-swizzled LDS to avoid bank conflicts;
// weights pre-packed into B-fragment order for coalesced global loads.
// ---------------------------------------------------------------------------

using f32x4 = __attribute__((ext_vector_type(4))) float;
using s16x8 = __attribute__((ext_vector_type(8))) short;

__device__ __forceinline__ unsigned short f2bf(float f) {
  union { float f; unsigned int u; } a; a.f = f;
  unsigned int r = (a.u + 0x7fffu + ((a.u >> 16) & 1u)) >> 16;   // RTNE
  return (unsigned short)r;
}
__device__ __forceinline__ float bf2f(unsigned short h) {
  union { unsigned int u; float f; } a; a.u = ((unsigned int)h) << 16; return a.f;
}
__device__ __forceinline__ void mfma16(f32x4& c, const s16x8& a, const s16x8& b) {
  // v_mfma_f32_16x16x32_bf16: A row = lane&15, k = (lane>>4)*8+j ; B col = lane&15,
  // k same; D col = lane&15, row = (lane>>4)*4 + reg.
  asm("v_mfma_f32_16x16x32_bf16 %0, %1, %2, %0" : "+v"(c) : "v"(a), "v"(b));
}
__device__ __forceinline__ float lrelu(float v) { return v > 0.f ? v : 0.01f * v; }
__device__ __forceinline__ float softplus1(float x) {
  return fmaxf(x, 0.f) + log1pf(expf(-fabsf(x)));
}

// Packed weight offsets (bf16 elements) inside workspace:
//   W1_in:   [0,        65536)         ksteps=8,  ncb=16
//   W1_h[i]: [65536*(1+i), ...)        ksteps=8,  ncb=16   (i=0..3)
//   Wc_in:   [327680,  368640)         ksteps=10, ncb=8    (K padded 280->320)
//   Wc_h[i]: [368640+i*16384, ...)     ksteps=4,  ncb=8
#define PACK_TOTAL 401408
#define RAD_BYTE_OFF (1 << 20)

__global__ void pack_kernel(const float* __restrict__ W1_in, const float* __restrict__ W1_h,
                            const float* __restrict__ Wc_in, const float* __restrict__ Wc_h,
                            unsigned short* __restrict__ wpack) {
  int p = blockIdx.x * 256 + threadIdx.x;
  if (p >= PACK_TOTAL) return;
  const float* src; int q, ncb, krows, ldn;
  if (p < 327680) {
    int mi = p >> 16; q = p & 65535;
    if (mi == 0) { src = W1_in; krows = 254; } else { src = W1_h + (mi - 1) * 65536; krows = 256; }
    ncb = 16; ldn = 256;
  } else if (p < 368640) {
    q = p - 327680; src = Wc_in; krows = 280; ncb = 8; ldn = 128;
  } else {
    int t = p - 368640; int mi = t >> 14; q = t & 16383;
    src = Wc_h + mi * 16384; krows = 128; ncb = 8; ldn = 128;
  }
  int frag = q >> 9, within = q & 511;
  int lane = within >> 3, j = within & 7;
  int cb = frag % ncb, ks = frag / ncb;
  int k = ks * 32 + ((lane >> 4) << 3) + j;
  int col = cb * 16 + (lane & 15);
  float v = (k < krows) ? src[k * ldn + col] : 0.f;
  wpack[p] = f2bf(v);
}

// One MLP layer for a 128-row tile: out = lrelu(in @ W + b), bf16 in LDS.
// LDS layout: row-major, XOR swizzle on 16B chunks: byte ^= (row&7)<<4.
template <int KSTEPS, int RF>
__device__ __forceinline__ void mlp_layer(
    const char* __restrict__ hin, int in_stride, char* __restrict__ hout, int out_stride,
    const s16x8* __restrict__ wp, int ncb, const float* __restrict__ bias,
    int lane, int rowbase, int cb0) {
  const int l15 = lane & 15, l4 = lane >> 4;
  float bcol[4];
#pragma unroll
  for (int cf = 0; cf < 4; ++cf) bcol[cf] = bias[(cb0 + cf) * 16 + l15];
  f32x4 acc[RF][4];
#pragma unroll
  for (int rf = 0; rf < RF; ++rf)
#pragma unroll
    for (int cf = 0; cf < 4; ++cf) acc[rf][cf] = (f32x4){0.f, 0.f, 0.f, 0.f};
#pragma unroll 2
  for (int ks = 0; ks < KSTEPS; ++ks) {
    s16x8 a[RF], b[4];
#pragma unroll
    for (int rf = 0; rf < RF; ++rf) {
      int row = rowbase + rf * 16 + l15;
      int chunk = (ks * 4 + l4) ^ (row & 7);
      a[rf] = *(const s16x8*)(hin + row * in_stride + chunk * 16);
    }
#pragma unroll
    for (int cf = 0; cf < 4; ++cf) b[cf] = wp[(ks * ncb + cb0 + cf) * 64 + lane];
#pragma unroll
    for (int rf = 0; rf < RF; ++rf)
#pragma unroll
      for (int cf = 0; cf < 4; ++cf) mfma16(acc[rf][cf], a[rf], b[cf]);
  }
#pragma unroll
  for (int rf = 0; rf < RF; ++rf) {
#pragma unroll
    for (int i = 0; i < 4; ++i) {
      int row = rowbase + rf * 16 + l4 * 4 + i;
      int sw = (row & 7) << 4;
      char* rowp = hout + row * out_stride;
#pragma unroll
      for (int cf = 0; cf < 4; ++cf) {
        int col = (cb0 + cf) * 16 + l15;
        float v = lrelu(acc[rf][cf][i] + bcol[cf]);
        *(unsigned short*)(rowp + ((col * 2) ^ sw)) = f2bf(v);
      }
    }
  }
}

// Phase A: per-point MLP (5 layers, 256-wide) + density + masked aggregation.
// Block: 512 thr (8 waves, 2M x 4N), M-tile = 128 rows = 16 points x k=8.
// LDS: two 64KB h-buffers + small arrays = 132160 B.
__global__ __launch_bounds__(512, 2) void phaseA_kernel(
    const float* __restrict__ rel_loc, const float* __restrict__ feat,
    const int* __restrict__ mask, const unsigned short* __restrict__ wpack,
    const float* __restrict__ b1_in, const float* __restrict__ b1_h,
    const float* __restrict__ Ws, const float* __restrict__ bs,
    float* __restrict__ out, unsigned short* __restrict__ rad) {
  extern __shared__ char smem[];
  char* buf0 = smem;
  char* buf1 = smem + 65536;
  float* wv = (float*)(smem + 131072);           // 128 normalized agg weights
  float* wsum = (float*)(smem + 131072 + 512);   // 16
  float* dpt = (float*)(smem + 131072 + 576);    // 128 density per point-sample
  const int tid = threadIdx.x;
  const int lane = tid & 63, wid = tid >> 6;
  const int wave_m = wid >> 2, wave_n = wid & 3;
  const int row0 = blockIdx.x * 128;

  // ---- build input features (bf16, swizzled) into buf0 ----
  for (int idx = tid; idx < 128 * 32; idx += 512) {
    int r = idx >> 5, d = idx & 31;
    float v = feat[(row0 + r) * 32 + d];
    int sw = (r & 7) << 4;
    char* rowp = buf0 + r * 512;
    *(unsigned short*)(rowp + ((d * 2) ^ sw)) = f2bf(v);
    float a = v;
#pragma unroll
    for (int f = 0; f < 3; ++f) {           // posenc(feat): cols 32 + (d*3+f)*2 + {0,1}
      float sv = sinf(a), cv = cosf(a);
      int jc = 32 + (d * 3 + f) * 2;
      *(unsigned short*)(rowp + ((jc * 2) ^ sw)) = f2bf(sv);
      *(unsigned short*)(rowp + (((jc + 1) * 2) ^ sw)) = f2bf(cv);
      a *= 2.f;
    }
  }
  for (int idx = tid; idx < 128 * 3; idx += 512) {
    int r = idx / 3, c = idx - r * 3;
    float v = rel_loc[(row0 + r) * 3 + c];
    int sw = (r & 7) << 4;
    char* rowp = buf0 + r * 512;
    float a = v;
#pragma unroll
    for (int f = 0; f < 5; ++f) {           // posenc(rel_loc): cols 224 + (c*5+f)*2 + {0,1}
      float sv = sinf(a), cv = cosf(a);
      int jc = 224 + (c * 5 + f) * 2;
      *(unsigned short*)(rowp + ((jc * 2) ^ sw)) = f2bf(sv);
      *(unsigned short*)(rowp + (((jc + 1) * 2) ^ sw)) = f2bf(cv);
      a *= 2.f;
    }
  }
  if (tid < 256) {                          // zero-pad cols 254,255
    int r = tid >> 1, cc = 254 + (tid & 1);
    *(unsigned short*)(buf0 + r * 512 + (((cc * 2)) ^ ((r & 7) << 4))) = 0;
  }
  if (tid < 128) {                          // raw aggregation weights
    float x = rel_loc[(row0 + tid) * 3 + 0];
    float y = rel_loc[(row0 + tid) * 3 + 1];
    float z = rel_loc[(row0 + tid) * 3 + 2];
    float dist = sqrtf(x * x + y * y + z * z);
    float m = (mask[row0 + tid] != 0) ? 1.f : 0.f;
    wv[tid] = m / fmaxf(dist, 1e-8f);
  }
  __syncthreads();
  if (tid < 16) {
    float s = 0.f;
#pragma unroll
    for (int k = 0; k < 8; ++k) s += wv[tid * 8 + k];
    wsum[tid] = fmaxf(s, 1e-8f);
  }
  __syncthreads();
  if (tid < 128) wv[tid] = wv[tid] / wsum[tid >> 3];

  // ---- 5 MLP layers, ping-pong buffers ----
  const char* hin = buf0;
  char* hout = buf1;
#pragma unroll 1
  for (int L = 0; L < 5; ++L) {
    __syncthreads();
    const s16x8* wp = (const s16x8*)(wpack + L * 65536);
    const float* bias = (L == 0) ? b1_in : (b1_h + (L - 1) * 256);
    mlp_layer<8, 4>(hin, 512, hout, 512, wp, 16, bias, lane, wave_m * 64, wave_n * 4);
    const char* t = hin; hin = hout; hout = (char*)t;
  }
  __syncthreads();
  // hin now holds h4 (post-lrelu), bf16 swizzled, stride 512.

  // ---- density per point-sample: softplus(h4 @ Ws + bs - 1) ----
  if (tid < 128) {
    float s = 0.f;
    const char* rowp = hin + tid * 512;
    int rsw = tid & 7;
    for (int c16 = 0; c16 < 32; ++c16) {
      int chunk = c16 ^ rsw;
      s16x8 v = *(const s16x8*)(rowp + chunk * 16);
#pragma unroll
      for (int j = 0; j < 8; ++j) s += bf2f((unsigned short)v[j]) * Ws[c16 * 8 + j];
    }
    dpt[tid] = softplus1(s + bs[0] - 1.f);
  }
  __syncthreads();

  // ---- masked weighted aggregation over k=8 ----
  for (int idx = tid; idx < 16 * 256; idx += 512) {
    int nn = idx >> 8, c = idx & 255;
    float s = 0.f;
#pragma unroll
    for (int k = 0; k < 8; ++k) {
      int r = nn * 8 + k;
      s += wv[r] * bf2f(*(const unsigned short*)(hin + r * 512 + ((c * 2) ^ ((r & 7) << 4))));
    }
    rad[(row0 / 8 + nn) * 256 + c] = f2bf(s);
  }
  if (tid < 16) {
    float s = 0.f;
#pragma unroll
    for (int k = 0; k < 8; ++k) s += wv[tid * 8 + k] * dpt[tid * 8 + k];
    out[(row0 / 8 + tid) * 4] = s;   // density output
  }
}

// Phase B: color MLP. Block: 512 thr (8 waves, 4M x 2N), M-tile 128 points.
// LDS: buf0 128x640B (K padded to 320) + buf1 128x256B = 114688 B.
__global__ __launch_bounds__(512, 2) void phaseB_kernel(
    const unsigned short* __restrict__ rad, const float* __restrict__ viewdir,
    const unsigned short* __restrict__ wpack, const float* __restrict__ bc_in,
    const float* __restrict__ bc_h, const float* __restrict__ Wc_out,
    const float* __restrict__ bc_out, float* __restrict__ out) {
  extern __shared__ char smem[];
  char* buf0 = smem;            // stride 640
  char* buf1 = smem + 81920;    // stride 256
  const int tid = threadIdx.x;
  const int lane = tid & 63, wid = tid >> 6;
  const int wave_m = wid >> 1, wave_n = wid & 1;
  const int g0 = blockIdx.x * 128;

  for (int idx = tid; idx < 128 * 32; idx += 512) {   // radiance cols 0..255
    int r = idx >> 5, c8 = idx & 31;
    s16x8 v = *(const s16x8*)(rad + (g0 + r) * 256 + c8 * 8);
    int chunk = c8 ^ (r & 7);
    *(s16x8*)(buf0 + r * 640 + chunk * 16) = v;
  }
  for (int idx = tid; idx < 128 * 3; idx += 512) {    // posenc(viewdir): cols 256..279
    int r = idx / 3, c = idx - r * 3;
    float v = viewdir[(g0 + r) * 3 + c];
    int sw = (r & 7) << 4;
    char* rowp = buf0 + r * 640;
    float a = v;
#pragma unroll
    for (int f = 0; f < 4; ++f) {
      float sv = sinf(a), cv = cosf(a);
      int jc = 256 + (c * 4 + f) * 2;
      *(unsigned short*)(rowp + ((jc * 2) ^ sw)) = f2bf(sv);
      *(unsigned short*)(rowp + (((jc + 1) * 2) ^ sw)) = f2bf(cv);
      a *= 2.f;
    }
  }
  for (int idx = tid; idx < 128 * 40; idx += 512) {   // zero-pad cols 280..319
    int r = idx / 40, c = 280 + (idx - r * 40);
    *(unsigned short*)(buf0 + r * 640 + ((c * 2) ^ ((r & 7) << 4))) = 0;
  }
  __syncthreads();
  mlp_layer<10, 2>(buf0, 640, buf1, 256, (const s16x8*)(wpack + 327680), 8, bc_in, lane, wave_m * 32, wave_n * 4);
  __syncthreads();
  mlp_layer<4, 2>(buf1, 256, buf0, 256, (const s16x8*)(wpack + 368640), 8, bc_h, lane, wave_m * 32, wave_n * 4);
  __syncthreads();
  mlp_layer<4, 2>(buf0, 256, buf1, 256, (const s16x8*)(wpack + 385024), 8, bc_h + 128, lane, wave_m * 32, wave_n * 4);
  __syncthreads();

  if (tid < 128) {   // final 128 -> 3 + sigmoid epilogue
    int r = tid, rsw = r & 7;
    const char* rowp = buf1 + r * 256;
    float d0 = 0.f, d1 = 0.f, d2 = 0.f;
    for (int c16 = 0; c16 < 16; ++c16) {
      int chunk = c16 ^ rsw;
      s16x8 v = *(const s16x8*)(rowp + chunk * 16);
#pragma unroll
      for (int j = 0; j < 8; ++j) {
        float hv = bf2f((unsigned short)v[j]);
        const float* wr = Wc_out + (c16 * 8 + j) * 3;
        d0 += hv * wr[0]; d1 += hv * wr[1]; d2 += hv * wr[2];
      }
    }
    float o[3] = { d0 + bc_out[0], d1 + bc_out[1], d2 + bc_out[2] };
#pragma unroll
    for (int ch = 0; ch < 3; ++ch) {
      float sg = 1.f / (1.f + expf(-o[ch]));
      out[(g0 + r) * 4 + 1 + ch] = sg * 1.002f - 0.001f;
    }
  }
}

extern "C" void kernel_launch(void* const* d_in, const int* in_sizes, int n_in,
                              void* d_out, int out_size, void* d_ws, size_t ws_size,
                              hipStream_t stream) {
  const float* rel_loc = (const float*)d_in[0];
  const float* feat    = (const float*)d_in[1];
  const int*   mask    = (const int*)d_in[2];   // bool in reference; harness delivers int32
  const float* viewdir = (const float*)d_in[3];
  const float* W1_in   = (const float*)d_in[4];
  const float* b1_in   = (const float*)d_in[5];
  const float* W1_h    = (const float*)d_in[6];
  const float* b1_h    = (const float*)d_in[7];
  const float* Ws      = (const float*)d_in[8];
  const float* bs      = (const float*)d_in[9];
  const float* Wc_in   = (const float*)d_in[10];
  const float* bc_in   = (const float*)d_in[11];
  const float* Wc_h    = (const float*)d_in[12];
  const float* bc_h    = (const float*)d_in[13];
  const float* Wc_out  = (const float*)d_in[14];
  const float* bc_out  = (const float*)d_in[15];
  float* out = (float*)d_out;
  unsigned short* wpack = (unsigned short*)d_ws;
  unsigned short* rad = (unsigned short*)((char*)d_ws + RAD_BYTE_OFF);

  const int n = in_sizes[3] / 3;          // 32768
  const int blocksA = n / 16;             // 2048  (128 point-samples per block)
  const int blocksB = n / 128;            // 256

  hipFuncSetAttribute((const void*)phaseA_kernel, hipFuncAttributeMaxDynamicSharedMemorySize, 132160);
  hipFuncSetAttribute((const void*)phaseB_kernel, hipFuncAttributeMaxDynamicSharedMemorySize, 114688);

  pack_kernel<<<(PACK_TOTAL + 255) / 256, 256, 0, stream>>>(W1_in, W1_h, Wc_in, Wc_h, wpack);
  phaseA_kernel<<<blocksA, 512, 132160, stream>>>(rel_loc, feat, mask, wpack, b1_in, b1_h, Ws, bs, out, rad);
  phaseB_kernel<<<blocksB, 512, 114688, stream>>>(rad, viewdir, wpack, bc_in, bc_h, Wc_out, bc_out, out);
}

// Round 3
// 322.045 us; speedup vs baseline: 1.2340x; 1.2340x over previous
//
#include <hip/hip_runtime.h>
#include <hip/hip_bf16.h>

// ---------------------------------------------------------------------------
// NeRF-style aggregator, MI355X (gfx950). R2 (resubmit — R2 bench never ran).
// Changes vs R1: swapped MFMA operands (D = W·X^T) so per-lane outputs are 4
// consecutive features -> packed cvt + ds_write_b64 epilogue; single in-place
// LDS buffer (66KB -> 2 blocks/CU); sincos+double-angle posenc; b64 agg.
// ---------------------------------------------------------------------------

using f32x4 = __attribute__((ext_vector_type(4))) float;
using s16x8 = __attribute__((ext_vector_type(8))) short;

__device__ __forceinline__ unsigned short f2bf(float f) {
  union { float f; unsigned int u; } a; a.f = f;
  unsigned int r = (a.u + 0x7fffu + ((a.u >> 16) & 1u)) >> 16;   // RTNE
  return (unsigned short)r;
}
__device__ __forceinline__ float bf2f(unsigned short h) {
  union { unsigned int u; float f; } a; a.u = ((unsigned int)h) << 16; return a.f;
}
__device__ __forceinline__ unsigned int pack2(float a, float b) {
  __hip_bfloat162 h2 = __float22bfloat162_rn(make_float2(a, b));
  union { __hip_bfloat162 h; unsigned int u; } cv; cv.h = h2; return cv.u;
}
__device__ __forceinline__ void mfma16(f32x4& c, const s16x8& a, const s16x8& b) {
  // v_mfma_f32_16x16x32_bf16. A: row=lane&15, k=(lane>>4)*8+j. B: col=lane&15,
  // k=(lane>>4)*8+j. D: col=lane&15, row=(lane>>4)*4+reg.
  asm("v_mfma_f32_16x16x32_bf16 %0, %1, %2, %0" : "+v"(c) : "v"(a), "v"(b));
}
__device__ __forceinline__ float lrelu(float v) { return fmaxf(v, 0.01f * v); }
__device__ __forceinline__ float softplus1(float x) {
  return fmaxf(x, 0.f) + log1pf(expf(-fabsf(x)));
}

// Packed weight offsets (bf16 elements) inside workspace (unchanged from R1):
//   W1_in:   [0, 65536)               ksteps=8,  nfb=16
//   W1_h[i]: [65536*(1+i), ...)       ksteps=8,  nfb=16   (i=0..3)
//   Wc_in:   [327680, 368640)         ksteps=10, nfb=8    (K padded 280->320)
//   Wc_h[i]: [368640+i*16384, ...)    ksteps=4,  nfb=8
#define PACK_TOTAL 401408
#define RAD_BYTE_OFF (1 << 20)

__global__ void pack_kernel(const float* __restrict__ W1_in, const float* __restrict__ W1_h,
                            const float* __restrict__ Wc_in, const float* __restrict__ Wc_h,
                            unsigned short* __restrict__ wpack) {
  int p = blockIdx.x * 256 + threadIdx.x;
  if (p >= PACK_TOTAL) return;
  const float* src; int q, ncb, krows, ldn;
  if (p < 327680) {
    int mi = p >> 16; q = p & 65535;
    if (mi == 0) { src = W1_in; krows = 254; } else { src = W1_h + (mi - 1) * 65536; krows = 256; }
    ncb = 16; ldn = 256;
  } else if (p < 368640) {
    q = p - 327680; src = Wc_in; krows = 280; ncb = 8; ldn = 128;
  } else {
    int t = p - 368640; int mi = t >> 14; q = t & 16383;
    src = Wc_h + mi * 16384; krows = 128; ncb = 8; ldn = 128;
  }
  int frag = q >> 9, within = q & 511;
  int lane = within >> 3, j = within & 7;
  int cb = frag % ncb, ks = frag / ncb;
  int k = ks * 32 + ((lane >> 4) << 3) + j;
  int col = cb * 16 + (lane & 15);
  float v = (k < krows) ? src[k * ldn + col] : 0.f;
  wpack[p] = f2bf(v);
}

// One MLP layer, IN-PLACE: reads all K cols of its sample rows, barrier, then
// overwrites with lrelu(X @ W + b). Swapped operands: A=weights, B=activations.
// Per lane D: sample = sbase*16 + (lane&15); 4 regs = 4 consecutive features
// at (fbase+ff)*16 + (lane>>4)*4.
template <int KSTEPS, int FF, int SF>
__device__ __forceinline__ void mlp_layer_T(
    char* __restrict__ buf, int stride,
    const s16x8* __restrict__ wp, int nfb, const float* __restrict__ bias,
    int lane, int fbase, int sbase) {
  const int l15 = lane & 15, l4 = lane >> 4;
  f32x4 acc[FF][SF];
#pragma unroll
  for (int ff = 0; ff < FF; ++ff)
#pragma unroll
    for (int sf = 0; sf < SF; ++sf) acc[ff][sf] = (f32x4){0.f, 0.f, 0.f, 0.f};
  char* rbase[SF]; int swv[SF];
#pragma unroll
  for (int sf = 0; sf < SF; ++sf) {
    int row = (sbase + sf) * 16 + l15;
    rbase[sf] = buf + row * stride;
    swv[sf] = (row & 7) << 4;
  }
#pragma unroll 2
  for (int ks = 0; ks < KSTEPS; ++ks) {
    s16x8 w[FF], x[SF];
#pragma unroll
    for (int ff = 0; ff < FF; ++ff) w[ff] = wp[(ks * nfb + fbase + ff) * 64 + lane];
    const int cb = (ks * 4 + l4) * 16;
#pragma unroll
    for (int sf = 0; sf < SF; ++sf) x[sf] = *(const s16x8*)(rbase[sf] + (cb ^ swv[sf]));
#pragma unroll
    for (int ff = 0; ff < FF; ++ff)
#pragma unroll
      for (int sf = 0; sf < SF; ++sf) mfma16(acc[ff][sf], w[ff], x[sf]);
  }
  __syncthreads();   // all reads done before any in-place write
#pragma unroll
  for (int ff = 0; ff < FF; ++ff) {
    const float4 b4 = *(const float4*)(bias + (fbase + ff) * 16 + l4 * 4);
    const int cb = (fbase + ff) * 32 + l4 * 8;
#pragma unroll
    for (int sf = 0; sf < SF; ++sf) {
      float v0 = lrelu(acc[ff][sf][0] + b4.x);
      float v1 = lrelu(acc[ff][sf][1] + b4.y);
      float v2 = lrelu(acc[ff][sf][2] + b4.z);
      float v3 = lrelu(acc[ff][sf][3] + b4.w);
      uint2 p; p.x = pack2(v0, v1); p.y = pack2(v2, v3);
      *(uint2*)(rbase[sf] + (cb ^ swv[sf])) = p;
    }
  }
}

// Phase A: per-sample MLP (5 layers, 256-wide) + density + masked aggregation.
// 512 thr = 8 waves (4 feature-waves x 2 sample-waves); tile = 128 samples.
// LDS: one 64KB buffer + small arrays = 66624 B -> 2 blocks/CU.
__global__ __launch_bounds__(512, 4) void phaseA_kernel(
    const float* __restrict__ rel_loc, const float* __restrict__ feat,
    const int* __restrict__ mask, const unsigned short* __restrict__ wpack,
    const float* __restrict__ b1_in, const float* __restrict__ b1_h,
    const float* __restrict__ Ws, const float* __restrict__ bs,
    float* __restrict__ out, unsigned short* __restrict__ rad) {
  extern __shared__ char smem[];
  char* buf = smem;                              // 128 x 512 B
  float* wv   = (float*)(smem + 65536);          // 128 normalized agg weights
  float* wsum = (float*)(smem + 65536 + 512);    // 16
  float* dpt  = (float*)(smem + 65536 + 576);    // 128
  const int tid = threadIdx.x;
  const int lane = tid & 63, wid = tid >> 6;
  const int fbase = (wid >> 1) * 4;   // 4 f-waves x FF=4 -> 16 ffrags (256 cols)
  const int sbase = (wid & 1) * 4;    // 2 s-waves x SF=4 -> 8 sfrags (128 rows)
  const int row0 = blockIdx.x * 128;

  // ---- build input features (bf16, XOR-swizzled) ----
  for (int idx = tid; idx < 128 * 32; idx += 512) {
    int r = idx >> 5, d = idx & 31;
    float v = feat[(row0 + r) * 32 + d];
    int sw = (r & 7) << 4;
    char* rowp = buf + r * 512;
    *(unsigned short*)(rowp + ((d * 2) ^ sw)) = f2bf(v);
    float s, c;
    __sincosf(v, &s, &c);
#pragma unroll
    for (int f = 0; f < 3; ++f) {                // cols 32 + (d*3+f)*2 + {0,1}
      *(unsigned int*)(rowp + ((64 + (d * 3 + f) * 4) ^ sw)) = pack2(s, c);
      float s2 = 2.f * s * c, c2 = 1.f - 2.f * s * s;
      s = s2; c = c2;
    }
  }
  for (int idx = tid; idx < 128 * 3; idx += 512) {
    int r = idx / 3, c = idx - r * 3;
    float v = rel_loc[(row0 + r) * 3 + c];
    int sw = (r & 7) << 4;
    char* rowp = buf + r * 512;
    float s, cc;
    __sincosf(v, &s, &cc);
#pragma unroll
    for (int f = 0; f < 5; ++f) {                // cols 224 + (c*5+f)*2 + {0,1}
      *(unsigned int*)(rowp + ((448 + (c * 5 + f) * 4) ^ sw)) = pack2(s, cc);
      float s2 = 2.f * s * cc, c2 = 1.f - 2.f * s * s;
      s = s2; cc = c2;
    }
  }
  if (tid < 128) {                  // zero-pad cols 254,255 + raw agg weights
    int r = tid;
    *(unsigned int*)(buf + r * 512 + (508 ^ ((r & 7) << 4))) = 0;
    float x = rel_loc[(row0 + r) * 3 + 0];
    float y = rel_loc[(row0 + r) * 3 + 1];
    float z = rel_loc[(row0 + r) * 3 + 2];
    float dist = sqrtf(x * x + y * y + z * z);
    float m = (mask[row0 + r] != 0) ? 1.f : 0.f;
    wv[r] = m / fmaxf(dist, 1e-8f);
  }
  __syncthreads();
  if (tid < 16) {
    float ssum = 0.f;
#pragma unroll
    for (int k = 0; k < 8; ++k) ssum += wv[tid * 8 + k];
    wsum[tid] = fmaxf(ssum, 1e-8f);
  }
  __syncthreads();
  if (tid < 128) wv[tid] = wv[tid] / wsum[tid >> 3];

  // ---- 5 MLP layers, in place ----
#pragma unroll 1
  for (int L = 0; L < 5; ++L) {
    __syncthreads();
    mlp_layer_T<8, 4, 4>(buf, 512, (const s16x8*)(wpack + L * 65536), 16,
                         (L == 0) ? b1_in : (b1_h + (L - 1) * 256), lane, fbase, sbase);
  }
  __syncthreads();

  // ---- density per sample: softplus(h4 @ Ws + bs - 1) ----
  if (tid < 128) {
    float s = 0.f;
    const char* rowp = buf + tid * 512;
    int rsw = (tid & 7) << 4;
    for (int c16 = 0; c16 < 32; ++c16) {
      s16x8 v = *(const s16x8*)(rowp + ((c16 * 16) ^ rsw));
#pragma unroll
      for (int j = 0; j < 8; ++j) s += bf2f((unsigned short)v[j]) * Ws[c16 * 8 + j];
    }
    dpt[tid] = softplus1(s + bs[0] - 1.f);
  }
  __syncthreads();

  // ---- masked weighted aggregation over k=8 (4 cols / thread, b64 reads) ----
  for (int idx = tid; idx < 16 * 64; idx += 512) {
    int nn = idx >> 6, c4 = idx & 63;
    float a0 = 0.f, a1 = 0.f, a2 = 0.f, a3 = 0.f;
#pragma unroll
    for (int k = 0; k < 8; ++k) {
      int r = nn * 8 + k;
      uint2 u = *(const uint2*)(buf + r * 512 + ((c4 * 8) ^ ((r & 7) << 4)));
      float w = wv[r];
      a0 += w * bf2f((unsigned short)(u.x & 0xffffu));
      a1 += w * bf2f((unsigned short)(u.x >> 16));
      a2 += w * bf2f((unsigned short)(u.y & 0xffffu));
      a3 += w * bf2f((unsigned short)(u.y >> 16));
    }
    uint2 p; p.x = pack2(a0, a1); p.y = pack2(a2, a3);
    *(uint2*)(rad + (row0 / 8 + nn) * 256 + c4 * 4) = p;
  }
  if (tid < 16) {
    float s = 0.f;
#pragma unroll
    for (int k = 0; k < 8; ++k) s += wv[tid * 8 + k] * dpt[tid * 8 + k];
    out[(row0 / 8 + tid) * 4] = s;   // density
  }
}

// Phase B: color MLP (280->128->128->128->3), 128 points/block, in-place
// 128x640B buffer (80KB). 8 waves = 2 f-waves x 4 s-waves.
__global__ __launch_bounds__(512, 2) void phaseB_kernel(
    const unsigned short* __restrict__ rad, const float* __restrict__ viewdir,
    const unsigned short* __restrict__ wpack, const float* __restrict__ bc_in,
    const float* __restrict__ bc_h, const float* __restrict__ Wc_out,
    const float* __restrict__ bc_out, float* __restrict__ out) {
  extern __shared__ char smem[];
  char* buf = smem;   // 128 x 640 B
  const int tid = threadIdx.x;
  const int lane = tid & 63, wid = tid >> 6;
  const int fbase = (wid >> 2) * 4;   // 2 f-waves x FF=4 -> 8 ffrags (128 cols)
  const int sbase = (wid & 3) * 2;    // 4 s-waves x SF=2 -> 8 sfrags (128 rows)
  const int g0 = blockIdx.x * 128;

  for (int idx = tid; idx < 128 * 32; idx += 512) {   // radiance cols 0..255
    int r = idx >> 5, c8 = idx & 31;
    s16x8 v = *(const s16x8*)(rad + (g0 + r) * 256 + c8 * 8);
    *(s16x8*)(buf + r * 640 + ((c8 * 16) ^ ((r & 7) << 4))) = v;
  }
  for (int idx = tid; idx < 128 * 3; idx += 512) {    // posenc(viewdir): cols 256..279
    int r = idx / 3, c = idx - r * 3;
    float v = viewdir[(g0 + r) * 3 + c];
    int sw = (r & 7) << 4;
    char* rowp = buf + r * 640;
    float s, cc;
    __sincosf(v, &s, &cc);
#pragma unroll
    for (int f = 0; f < 4; ++f) {
      *(unsigned int*)(rowp + ((512 + (c * 4 + f) * 4) ^ sw)) = pack2(s, cc);
      float s2 = 2.f * s * cc, c2 = 1.f - 2.f * s * s;
      s = s2; cc = c2;
    }
  }
  for (int idx = tid; idx < 128 * 20; idx += 512) {   // zero cols 280..319
    int r = idx / 20, i = idx - r * 20;
    *(unsigned int*)(buf + r * 640 + ((560 + i * 4) ^ ((r & 7) << 4))) = 0;
  }
  __syncthreads();
  mlp_layer_T<10, 4, 2>(buf, 640, (const s16x8*)(wpack + 327680), 8, bc_in, lane, fbase, sbase);
  __syncthreads();
  mlp_layer_T<4, 4, 2>(buf, 640, (const s16x8*)(wpack + 368640), 8, bc_h, lane, fbase, sbase);
  __syncthreads();
  mlp_layer_T<4, 4, 2>(buf, 640, (const s16x8*)(wpack + 385024), 8, bc_h + 128, lane, fbase, sbase);
  __syncthreads();

  if (tid < 128) {   // final 128 -> 3 + sigmoid epilogue
    int r = tid, rsw = (r & 7) << 4;
    const char* rowp = buf + r * 640;
    float d0 = 0.f, d1 = 0.f, d2 = 0.f;
    for (int c16 = 0; c16 < 16; ++c16) {
      s16x8 v = *(const s16x8*)(rowp + ((c16 * 16) ^ rsw));
#pragma unroll
      for (int j = 0; j < 8; ++j) {
        float hv = bf2f((unsigned short)v[j]);
        const float* wr = Wc_out + (c16 * 8 + j) * 3;
        d0 += hv * wr[0]; d1 += hv * wr[1]; d2 += hv * wr[2];
      }
    }
    float o0 = d0 + bc_out[0], o1 = d1 + bc_out[1], o2 = d2 + bc_out[2];
    out[(g0 + r) * 4 + 1] = 1.002f / (1.f + __expf(-o0)) - 0.001f;
    out[(g0 + r) * 4 + 2] = 1.002f / (1.f + __expf(-o1)) - 0.001f;
    out[(g0 + r) * 4 + 3] = 1.002f / (1.f + __expf(-o2)) - 0.001f;
  }
}

extern "C" void kernel_launch(void* const* d_in, const int* in_sizes, int n_in,
                              void* d_out, int out_size, void* d_ws, size_t ws_size,
                              hipStream_t stream) {
  const float* rel_loc = (const float*)d_in[0];
  const float* feat    = (const float*)d_in[1];
  const int*   mask    = (const int*)d_in[2];
  const float* viewdir = (const float*)d_in[3];
  const float* W1_in   = (const float*)d_in[4];
  const float* b1_in   = (const float*)d_in[5];
  const float* W1_h    = (const float*)d_in[6];
  const float* b1_h    = (const float*)d_in[7];
  const float* Ws      = (const float*)d_in[8];
  const float* bs      = (const float*)d_in[9];
  const float* Wc_in   = (const float*)d_in[10];
  const float* bc_in   = (const float*)d_in[11];
  const float* Wc_h    = (const float*)d_in[12];
  const float* bc_h    = (const float*)d_in[13];
  const float* Wc_out  = (const float*)d_in[14];
  const float* bc_out  = (const float*)d_in[15];
  float* out = (float*)d_out;
  unsigned short* wpack = (unsigned short*)d_ws;
  unsigned short* rad = (unsigned short*)((char*)d_ws + RAD_BYTE_OFF);

  const int n = in_sizes[3] / 3;          // 32768 points
  const int blocksA = n * 8 / 128;        // 2048
  const int blocksB = n / 128;            // 256

  hipFuncSetAttribute((const void*)phaseA_kernel, hipFuncAttributeMaxDynamicSharedMemorySize, 66624);
  hipFuncSetAttribute((const void*)phaseB_kernel, hipFuncAttributeMaxDynamicSharedMemorySize, 81920);

  pack_kernel<<<(PACK_TOTAL + 255) / 256, 256, 0, stream>>>(W1_in, W1_h, Wc_in, Wc_h, wpack);
  phaseA_kernel<<<blocksA, 512, 66624, stream>>>(rel_loc, feat, mask, wpack, b1_in, b1_h, Ws, bs, out, rad);
  phaseB_kernel<<<blocksB, 512, 81920, stream>>>(rad, viewdir, wpack, bc_in, bc_h, Wc_out, bc_out, out);
}

// Round 4
// 309.538 us; speedup vs baseline: 1.2838x; 1.0404x over previous
//
#include <hip/hip_runtime.h>
#include <hip/hip_bf16.h>

// ---------------------------------------------------------------------------
// NeRF-style aggregator, MI355X (gfx950). R4.
// Changes vs R3: 64-sample tiles (32KB LDS -> 3 blocks/CU, occupancy ~70%);
// wave shape FF=2/SF=4 (8 f-waves, no s-wave weight duplication -> L2 weight
// traffic unchanged); phaseB also 64-point tiles (512 blocks, 2/CU).
// ---------------------------------------------------------------------------

using f32x4 = __attribute__((ext_vector_type(4))) float;
using s16x8 = __attribute__((ext_vector_type(8))) short;

__device__ __forceinline__ unsigned short f2bf(float f) {
  union { float f; unsigned int u; } a; a.f = f;
  unsigned int r = (a.u + 0x7fffu + ((a.u >> 16) & 1u)) >> 16;   // RTNE
  return (unsigned short)r;
}
__device__ __forceinline__ float bf2f(unsigned short h) {
  union { unsigned int u; float f; } a; a.u = ((unsigned int)h) << 16; return a.f;
}
__device__ __forceinline__ unsigned int pack2(float a, float b) {
  __hip_bfloat162 h2 = __float22bfloat162_rn(make_float2(a, b));
  union { __hip_bfloat162 h; unsigned int u; } cv; cv.h = h2; return cv.u;
}
__device__ __forceinline__ void mfma16(f32x4& c, const s16x8& a, const s16x8& b) {
  // v_mfma_f32_16x16x32_bf16. A: row=lane&15, k=(lane>>4)*8+j. B: col=lane&15,
  // k=(lane>>4)*8+j. D: col=lane&15, row=(lane>>4)*4+reg.
  asm("v_mfma_f32_16x16x32_bf16 %0, %1, %2, %0" : "+v"(c) : "v"(a), "v"(b));
}
__device__ __forceinline__ float lrelu(float v) { return fmaxf(v, 0.01f * v); }
__device__ __forceinline__ float softplus1(float x) {
  return fmaxf(x, 0.f) + log1pf(expf(-fabsf(x)));
}

// Packed weight offsets (bf16 elements) inside workspace (unchanged):
//   W1_in:   [0, 65536)               ksteps=8,  nfb=16
//   W1_h[i]: [65536*(1+i), ...)       ksteps=8,  nfb=16   (i=0..3)
//   Wc_in:   [327680, 368640)         ksteps=10, nfb=8    (K padded 280->320)
//   Wc_h[i]: [368640+i*16384, ...)    ksteps=4,  nfb=8
#define PACK_TOTAL 401408
#define RAD_BYTE_OFF (1 << 20)

__global__ void pack_kernel(const float* __restrict__ W1_in, const float* __restrict__ W1_h,
                            const float* __restrict__ Wc_in, const float* __restrict__ Wc_h,
                            unsigned short* __restrict__ wpack) {
  int p = blockIdx.x * 256 + threadIdx.x;
  if (p >= PACK_TOTAL) return;
  const float* src; int q, ncb, krows, ldn;
  if (p < 327680) {
    int mi = p >> 16; q = p & 65535;
    if (mi == 0) { src = W1_in; krows = 254; } else { src = W1_h + (mi - 1) * 65536; krows = 256; }
    ncb = 16; ldn = 256;
  } else if (p < 368640) {
    q = p - 327680; src = Wc_in; krows = 280; ncb = 8; ldn = 128;
  } else {
    int t = p - 368640; int mi = t >> 14; q = t & 16383;
    src = Wc_h + mi * 16384; krows = 128; ncb = 8; ldn = 128;
  }
  int frag = q >> 9, within = q & 511;
  int lane = within >> 3, j = within & 7;
  int cb = frag % ncb, ks = frag / ncb;
  int k = ks * 32 + ((lane >> 4) << 3) + j;
  int col = cb * 16 + (lane & 15);
  float v = (k < krows) ? src[k * ldn + col] : 0.f;
  wpack[p] = f2bf(v);
}

// One MLP layer, IN-PLACE. Swapped operands: A=weights (global), B=activations
// (LDS). Per lane D: sample = (sbase+sf)*16 + (lane&15); 4 regs = 4 consecutive
// features at (fbase+ff)*16 + (lane>>4)*4.
template <int KSTEPS, int FF, int SF>
__device__ __forceinline__ void mlp_layer_T(
    char* __restrict__ buf, int stride,
    const s16x8* __restrict__ wp, int nfb, const float* __restrict__ bias,
    int lane, int fbase, int sbase) {
  const int l15 = lane & 15, l4 = lane >> 4;
  f32x4 acc[FF][SF];
#pragma unroll
  for (int ff = 0; ff < FF; ++ff)
#pragma unroll
    for (int sf = 0; sf < SF; ++sf) acc[ff][sf] = (f32x4){0.f, 0.f, 0.f, 0.f};
  char* rbase[SF]; int swv[SF];
#pragma unroll
  for (int sf = 0; sf < SF; ++sf) {
    int row = (sbase + sf) * 16 + l15;
    rbase[sf] = buf + row * stride;
    swv[sf] = (row & 7) << 4;
  }
#pragma unroll 2
  for (int ks = 0; ks < KSTEPS; ++ks) {
    s16x8 w[FF], x[SF];
#pragma unroll
    for (int ff = 0; ff < FF; ++ff) w[ff] = wp[(ks * nfb + fbase + ff) * 64 + lane];
    const int cb = (ks * 4 + l4) * 16;
#pragma unroll
    for (int sf = 0; sf < SF; ++sf) x[sf] = *(const s16x8*)(rbase[sf] + (cb ^ swv[sf]));
#pragma unroll
    for (int ff = 0; ff < FF; ++ff)
#pragma unroll
      for (int sf = 0; sf < SF; ++sf) mfma16(acc[ff][sf], w[ff], x[sf]);
  }
  __syncthreads();   // all reads done before any in-place write
#pragma unroll
  for (int ff = 0; ff < FF; ++ff) {
    const float4 b4 = *(const float4*)(bias + (fbase + ff) * 16 + l4 * 4);
    const int cb = (fbase + ff) * 32 + l4 * 8;
#pragma unroll
    for (int sf = 0; sf < SF; ++sf) {
      float v0 = lrelu(acc[ff][sf][0] + b4.x);
      float v1 = lrelu(acc[ff][sf][1] + b4.y);
      float v2 = lrelu(acc[ff][sf][2] + b4.z);
      float v3 = lrelu(acc[ff][sf][3] + b4.w);
      uint2 p; p.x = pack2(v0, v1); p.y = pack2(v2, v3);
      *(uint2*)(rbase[sf] + (cb ^ swv[sf])) = p;
    }
  }
}

// Phase A: per-sample MLP (5 layers, 256-wide) + density + masked aggregation.
// 512 thr = 8 f-waves (FF=2), each covering all 64 sample rows (SF=4).
// LDS: 64x512 buffer + small arrays = 33312 B -> 3 blocks/CU at VGPR<=85.
__global__ __launch_bounds__(512, 6) void phaseA_kernel(
    const float* __restrict__ rel_loc, const float* __restrict__ feat,
    const int* __restrict__ mask, const unsigned short* __restrict__ wpack,
    const float* __restrict__ b1_in, const float* __restrict__ b1_h,
    const float* __restrict__ Ws, const float* __restrict__ bs,
    float* __restrict__ out, unsigned short* __restrict__ rad) {
  extern __shared__ char smem[];
  char* buf = smem;                              // 64 x 512 B
  float* wv   = (float*)(smem + 32768);          // 64 normalized agg weights
  float* wsum = (float*)(smem + 32768 + 256);    // 8
  float* dpt  = (float*)(smem + 32768 + 288);    // 64
  const int tid = threadIdx.x;
  const int lane = tid & 63, wid = tid >> 6;
  const int fbase = wid * 2;          // 8 f-waves x FF=2 -> 16 ffrags (256 cols)
  const int row0 = blockIdx.x * 64;

  // ---- build input features (bf16, XOR-swizzled) ----
  for (int idx = tid; idx < 64 * 32; idx += 512) {
    int r = idx >> 5, d = idx & 31;
    float v = feat[(row0 + r) * 32 + d];
    int sw = (r & 7) << 4;
    char* rowp = buf + r * 512;
    *(unsigned short*)(rowp + ((d * 2) ^ sw)) = f2bf(v);
    float s, c;
    __sincosf(v, &s, &c);
#pragma unroll
    for (int f = 0; f < 3; ++f) {                // cols 32 + (d*3+f)*2 + {0,1}
      *(unsigned int*)(rowp + ((64 + (d * 3 + f) * 4) ^ sw)) = pack2(s, c);
      float s2 = 2.f * s * c, c2 = 1.f - 2.f * s * s;
      s = s2; c = c2;
    }
  }
  for (int idx = tid; idx < 64 * 3; idx += 512) {
    int r = idx / 3, c = idx - r * 3;
    float v = rel_loc[(row0 + r) * 3 + c];
    int sw = (r & 7) << 4;
    char* rowp = buf + r * 512;
    float s, cc;
    __sincosf(v, &s, &cc);
#pragma unroll
    for (int f = 0; f < 5; ++f) {                // cols 224 + (c*5+f)*2 + {0,1}
      *(unsigned int*)(rowp + ((448 + (c * 5 + f) * 4) ^ sw)) = pack2(s, cc);
      float s2 = 2.f * s * cc, c2 = 1.f - 2.f * s * s;
      s = s2; cc = c2;
    }
  }
  if (tid < 64) {                  // zero-pad cols 254,255 + raw agg weights
    int r = tid;
    *(unsigned int*)(buf + r * 512 + (508 ^ ((r & 7) << 4))) = 0;
    float x = rel_loc[(row0 + r) * 3 + 0];
    float y = rel_loc[(row0 + r) * 3 + 1];
    float z = rel_loc[(row0 + r) * 3 + 2];
    float dist = sqrtf(x * x + y * y + z * z);
    float m = (mask[row0 + r] != 0) ? 1.f : 0.f;
    wv[r] = m / fmaxf(dist, 1e-8f);
  }
  __syncthreads();
  if (tid < 8) {
    float ssum = 0.f;
#pragma unroll
    for (int k = 0; k < 8; ++k) ssum += wv[tid * 8 + k];
    wsum[tid] = fmaxf(ssum, 1e-8f);
  }
  __syncthreads();
  if (tid < 64) wv[tid] = wv[tid] / wsum[tid >> 3];

  // ---- 5 MLP layers, in place ----
#pragma unroll 1
  for (int L = 0; L < 5; ++L) {
    __syncthreads();
    mlp_layer_T<8, 2, 4>(buf, 512, (const s16x8*)(wpack + L * 65536), 16,
                         (L == 0) ? b1_in : (b1_h + (L - 1) * 256), lane, fbase, 0);
  }
  __syncthreads();

  // ---- density per sample: softplus(h4 @ Ws + bs - 1) ----
  if (tid < 64) {
    float s = 0.f;
    const char* rowp = buf + tid * 512;
    int rsw = (tid & 7) << 4;
    for (int c16 = 0; c16 < 32; ++c16) {
      s16x8 v = *(const s16x8*)(rowp + ((c16 * 16) ^ rsw));
#pragma unroll
      for (int j = 0; j < 8; ++j) s += bf2f((unsigned short)v[j]) * Ws[c16 * 8 + j];
    }
    dpt[tid] = softplus1(s + bs[0] - 1.f);
  }
  __syncthreads();

  // ---- masked weighted aggregation over k=8 (one uint2 col-group/thread) ----
  {
    int nn = tid >> 6, c4 = tid & 63;          // 8 points x 64 col-groups = 512
    float a0 = 0.f, a1 = 0.f, a2 = 0.f, a3 = 0.f;
#pragma unroll
    for (int k = 0; k < 8; ++k) {
      int r = nn * 8 + k;
      uint2 u = *(const uint2*)(buf + r * 512 + ((c4 * 8) ^ ((r & 7) << 4)));
      float w = wv[r];
      a0 += w * bf2f((unsigned short)(u.x & 0xffffu));
      a1 += w * bf2f((unsigned short)(u.x >> 16));
      a2 += w * bf2f((unsigned short)(u.y & 0xffffu));
      a3 += w * bf2f((unsigned short)(u.y >> 16));
    }
    uint2 p; p.x = pack2(a0, a1); p.y = pack2(a2, a3);
    *(uint2*)(rad + (row0 / 8 + nn) * 256 + c4 * 4) = p;
  }
  if (tid < 8) {
    float s = 0.f;
#pragma unroll
    for (int k = 0; k < 8; ++k) s += wv[tid * 8 + k] * dpt[tid * 8 + k];
    out[(row0 / 8 + tid) * 4] = s;   // density
  }
}

// Phase B: color MLP (280->128->128->128->3), 64 points/block -> 512 blocks.
// 8 waves = 4 f-waves (FF=2) x 2 s-waves (SF=2). LDS 64x640 = 40960 B.
__global__ __launch_bounds__(512, 4) void phaseB_kernel(
    const unsigned short* __restrict__ rad, const float* __restrict__ viewdir,
    const unsigned short* __restrict__ wpack, const float* __restrict__ bc_in,
    const float* __restrict__ bc_h, const float* __restrict__ Wc_out,
    const float* __restrict__ bc_out, float* __restrict__ out) {
  extern __shared__ char smem[];
  char* buf = smem;   // 64 x 640 B
  const int tid = threadIdx.x;
  const int lane = tid & 63, wid = tid >> 6;
  const int fbase = (wid >> 1) * 2;   // 4 f-waves x FF=2 -> 8 ffrags (128 cols)
  const int sbase = (wid & 1) * 2;    // 2 s-waves x SF=2 -> 4 sfrags (64 rows)
  const int g0 = blockIdx.x * 64;

  for (int idx = tid; idx < 64 * 32; idx += 512) {    // radiance cols 0..255
    int r = idx >> 5, c8 = idx & 31;
    s16x8 v = *(const s16x8*)(rad + (g0 + r) * 256 + c8 * 8);
    *(s16x8*)(buf + r * 640 + ((c8 * 16) ^ ((r & 7) << 4))) = v;
  }
  for (int idx = tid; idx < 64 * 3; idx += 512) {     // posenc(viewdir): cols 256..279
    int r = idx / 3, c = idx - r * 3;
    float v = viewdir[(g0 + r) * 3 + c];
    int sw = (r & 7) << 4;
    char* rowp = buf + r * 640;
    float s, cc;
    __sincosf(v, &s, &cc);
#pragma unroll
    for (int f = 0; f < 4; ++f) {
      *(unsigned int*)(rowp + ((512 + (c * 4 + f) * 4) ^ sw)) = pack2(s, cc);
      float s2 = 2.f * s * cc, c2 = 1.f - 2.f * s * s;
      s = s2; cc = c2;
    }
  }
  for (int idx = tid; idx < 64 * 20; idx += 512) {    // zero cols 280..319
    int r = idx / 20, i = idx - r * 20;
    *(unsigned int*)(buf + r * 640 + ((560 + i * 4) ^ ((r & 7) << 4))) = 0;
  }
  __syncthreads();
  mlp_layer_T<10, 2, 2>(buf, 640, (const s16x8*)(wpack + 327680), 8, bc_in, lane, fbase, sbase);
  __syncthreads();
  mlp_layer_T<4, 2, 2>(buf, 640, (const s16x8*)(wpack + 368640), 8, bc_h, lane, fbase, sbase);
  __syncthreads();
  mlp_layer_T<4, 2, 2>(buf, 640, (const s16x8*)(wpack + 385024), 8, bc_h + 128, lane, fbase, sbase);
  __syncthreads();

  if (tid < 64) {   // final 128 -> 3 + sigmoid epilogue
    int r = tid, rsw = (r & 7) << 4;
    const char* rowp = buf + r * 640;
    float d0 = 0.f, d1 = 0.f, d2 = 0.f;
    for (int c16 = 0; c16 < 16; ++c16) {
      s16x8 v = *(const s16x8*)(rowp + ((c16 * 16) ^ rsw));
#pragma unroll
      for (int j = 0; j < 8; ++j) {
        float hv = bf2f((unsigned short)v[j]);
        const float* wr = Wc_out + (c16 * 8 + j) * 3;
        d0 += hv * wr[0]; d1 += hv * wr[1]; d2 += hv * wr[2];
      }
    }
    float o0 = d0 + bc_out[0], o1 = d1 + bc_out[1], o2 = d2 + bc_out[2];
    out[(g0 + r) * 4 + 1] = 1.002f / (1.f + __expf(-o0)) - 0.001f;
    out[(g0 + r) * 4 + 2] = 1.002f / (1.f + __expf(-o1)) - 0.001f;
    out[(g0 + r) * 4 + 3] = 1.002f / (1.f + __expf(-o2)) - 0.001f;
  }
}

extern "C" void kernel_launch(void* const* d_in, const int* in_sizes, int n_in,
                              void* d_out, int out_size, void* d_ws, size_t ws_size,
                              hipStream_t stream) {
  const float* rel_loc = (const float*)d_in[0];
  const float* feat    = (const float*)d_in[1];
  const int*   mask    = (const int*)d_in[2];
  const float* viewdir = (const float*)d_in[3];
  const float* W1_in   = (const float*)d_in[4];
  const float* b1_in   = (const float*)d_in[5];
  const float* W1_h    = (const float*)d_in[6];
  const float* b1_h    = (const float*)d_in[7];
  const float* Ws      = (const float*)d_in[8];
  const float* bs      = (const float*)d_in[9];
  const float* Wc_in   = (const float*)d_in[10];
  const float* bc_in   = (const float*)d_in[11];
  const float* Wc_h    = (const float*)d_in[12];
  const float* bc_h    = (const float*)d_in[13];
  const float* Wc_out  = (const float*)d_in[14];
  const float* bc_out  = (const float*)d_in[15];
  float* out = (float*)d_out;
  unsigned short* wpack = (unsigned short*)d_ws;
  unsigned short* rad = (unsigned short*)((char*)d_ws + RAD_BYTE_OFF);

  const int n = in_sizes[3] / 3;          // 32768 points
  const int blocksA = n * 8 / 64;         // 4096
  const int blocksB = n / 64;             // 512

  hipFuncSetAttribute((const void*)phaseA_kernel, hipFuncAttributeMaxDynamicSharedMemorySize, 33312);
  hipFuncSetAttribute((const void*)phaseB_kernel, hipFuncAttributeMaxDynamicSharedMemorySize, 40960);

  pack_kernel<<<(PACK_TOTAL + 255) / 256, 256, 0, stream>>>(W1_in, W1_h, Wc_in, Wc_h, wpack);
  phaseA_kernel<<<blocksA, 512, 33312, stream>>>(rel_loc, feat, mask, wpack, b1_in, b1_h, Ws, bs, out, rad);
  phaseB_kernel<<<blocksB, 512, 40960, stream>>>(rad, viewdir, wpack, bc_in, bc_h, Wc_out, bc_out, out);
}